// Round 3
// baseline (936.153 us; speedup 1.0000x reference)
//
#include <hip/hip_runtime.h>
#include <math.h>

// Problem constants (shapes follow the reference; N and E derived from in_sizes)
#define DIMX   256
#define HEADS  16
#define QKD    8
#define DH     128           // HEADS*QKD
#define QKVW   512           // 2*DH + DIMX
#define INRPE  18
#define SCALE  0.35355339059327373f   // 8^-0.5

// ---------------------------------------------------------------------------
// Kernel 1: qkv = x @ Wqkv + b ; q-part pre-scaled by SCALE.
// Row layout (512 floats): [q*SCALE (128) | k (128) | v (256)]
// 128x128 tile, 256 threads, 8x8 microtile. B fragment split into two 4-spans
// (cols tx*4 and 64+tx*4) so LDS reads alias only 2-way (free on gfx950).
// ---------------------------------------------------------------------------
__global__ __launch_bounds__(256) void qkv_gemm(
    const float* __restrict__ x, const float* __restrict__ W,
    const float* __restrict__ bias, float* __restrict__ qkv, int Nn)
{
    __shared__ float As[16][132];   // A^T tile: As[k][row]
    __shared__ float Bs[16][132];   // B tile:  Bs[k][col]

    int tid  = threadIdx.x;
    int row0 = blockIdx.x * 128;
    int col0 = blockIdx.y * 128;
    int tx = tid & 15, ty = tid >> 4;

    float acc[8][8] = {};

    for (int k0 = 0; k0 < DIMX; k0 += 16) {
        // A tile: 128 rows x 16 k = 512 float4 loads, 2 per thread
        #pragma unroll
        for (int r = 0; r < 2; r++) {
            int idx  = tid + r * 256;
            int arow = idx >> 2, acol = (idx & 3) * 4;
            float4 av = make_float4(0.f, 0.f, 0.f, 0.f);
            int grow = row0 + arow;
            if (grow < Nn) av = *(const float4*)&x[(size_t)grow * DIMX + k0 + acol];
            As[acol + 0][arow] = av.x;
            As[acol + 1][arow] = av.y;
            As[acol + 2][arow] = av.z;
            As[acol + 3][arow] = av.w;
        }
        // B tile: 16 k x 128 cols = 512 float4 loads, 2 per thread
        #pragma unroll
        for (int r = 0; r < 2; r++) {
            int idx  = tid + r * 256;
            int brow = idx >> 5, bcol = (idx & 31) * 4;
            *(float4*)&Bs[brow][bcol] =
                *(const float4*)&W[(size_t)(k0 + brow) * QKVW + col0 + bcol];
        }
        __syncthreads();
        #pragma unroll
        for (int kk = 0; kk < 16; kk++) {
            float a0[8], b0[8];
            *(float4*)&a0[0] = *(const float4*)&As[kk][ty * 8];
            *(float4*)&a0[4] = *(const float4*)&As[kk][ty * 8 + 4];
            *(float4*)&b0[0] = *(const float4*)&Bs[kk][tx * 4];
            *(float4*)&b0[4] = *(const float4*)&Bs[kk][64 + tx * 4];
            #pragma unroll
            for (int i = 0; i < 8; i++)
                #pragma unroll
                for (int j = 0; j < 8; j++)
                    acc[i][j] = fmaf(a0[i], b0[j], acc[i][j]);
        }
        __syncthreads();
    }

    // epilogue: bias, scale q-columns (block col0==0 is entirely q), store
    float sc = (blockIdx.y == 0) ? SCALE : 1.0f;
    float4 bv0 = *(const float4*)&bias[col0 + tx * 4];
    float4 bv1 = *(const float4*)&bias[col0 + 64 + tx * 4];
    #pragma unroll
    for (int i = 0; i < 8; i++) {
        int grow = row0 + ty * 8 + i;
        if (grow < Nn) {
            float4 o0, o1;
            o0.x = (acc[i][0] + bv0.x) * sc;
            o0.y = (acc[i][1] + bv0.y) * sc;
            o0.z = (acc[i][2] + bv0.z) * sc;
            o0.w = (acc[i][3] + bv0.w) * sc;
            o1.x = (acc[i][4] + bv1.x) * sc;
            o1.y = (acc[i][5] + bv1.y) * sc;
            o1.z = (acc[i][6] + bv1.z) * sc;
            o1.w = (acc[i][7] + bv1.w) * sc;
            *(float4*)&qkv[(size_t)grow * QKVW + col0 + tx * 4] = o0;
            *(float4*)&qkv[(size_t)grow * QKVW + col0 + 64 + tx * 4] = o1;
        }
    }
}

// ---------------------------------------------------------------------------
// CSR build: count -> scan -> scatter (grouped by source node s)
// ---------------------------------------------------------------------------
__global__ void count_kernel(const int* __restrict__ ei, int* __restrict__ deg, int E)
{
    int e = blockIdx.x * blockDim.x + threadIdx.x;
    if (e < E) atomicAdd(&deg[ei[e]], 1);
}

__global__ __launch_bounds__(1024) void scan_kernel(
    const int* __restrict__ deg, int* __restrict__ off, int n)
{
    __shared__ int part[1024];
    int tid = threadIdx.x;
    int chunk = (n + 1023) / 1024;
    int s = tid * chunk;
    int epos = min(s + chunk, n);
    int sum = 0;
    for (int i = s; i < epos; i++) sum += deg[i];
    part[tid] = sum;
    __syncthreads();
    for (int d = 1; d < 1024; d <<= 1) {
        int v = (tid >= d) ? part[tid - d] : 0;
        __syncthreads();
        part[tid] += v;
        __syncthreads();
    }
    int run = part[tid] - sum;   // exclusive base
    for (int i = s; i < epos; i++) { off[i] = run; run += deg[i]; }
    if (tid == 1023) off[n] = run;
}

__global__ void scatter_kernel(const int* __restrict__ ei,
                               const int* __restrict__ off, int* __restrict__ cur,
                               int2* __restrict__ elist, int E)
{
    int e = blockIdx.x * blockDim.x + threadIdx.x;
    if (e < E) {
        int s = ei[e];
        int t = ei[E + e];
        int pos = atomicAdd(&cur[s], 1);
        elist[off[s] + pos] = make_int2(e, t);
    }
}

// ---------------------------------------------------------------------------
// Kernel 2a: edge-parallel compat. Grid-stride, one wave per edge per step.
// Lane l handles head h=l>>2, qk dims 2l,2l+1. RPE weight columns stay in
// 72 VGPRs and amortize over ~E/8192 edges per wave. Independent edges give
// the latency hiding the node-centric loop lacked.
// ---------------------------------------------------------------------------
__global__ __launch_bounds__(256) void compat_kernel(
    const float* __restrict__ qkv, const int* __restrict__ ei,
    const float* __restrict__ edge_attr,
    const float* __restrict__ Wq_rpe, const float* __restrict__ bq_rpe,
    const float* __restrict__ Wk_rpe, const float* __restrict__ bk_rpe,
    float* __restrict__ compat, int E)
{
    int lane = threadIdx.x & 63;
    int wid  = (blockIdx.x * blockDim.x + threadIdx.x) >> 6;
    int nw   = (gridDim.x * blockDim.x) >> 6;
    int c0   = lane * 2;

    float wq0[INRPE], wq1[INRPE], wk0[INRPE], wk1[INRPE];
    #pragma unroll
    for (int j = 0; j < INRPE; j++) {
        wq0[j] = Wq_rpe[j * DH + c0];
        wq1[j] = Wq_rpe[j * DH + c0 + 1];
        wk0[j] = Wk_rpe[j * DH + c0];
        wk1[j] = Wk_rpe[j * DH + c0 + 1];
    }
    float bq0 = bq_rpe[c0], bq1 = bq_rpe[c0 + 1];
    float bk0 = bk_rpe[c0], bk1 = bk_rpe[c0 + 1];

    for (int e = wid; e < E; e += nw) {
        int s = ei[e];
        int t = ei[E + e];

        const float2* ea2 = (const float2*)(edge_attr + (size_t)e * INRPE);
        float a[INRPE];
        #pragma unroll
        for (int j = 0; j < 9; j++) {
            float2 v = ea2[j];
            a[2 * j] = v.x;
            a[2 * j + 1] = v.y;
        }

        float qr0 = bq0, qr1 = bq1, kr0 = bk0, kr1 = bk1;
        #pragma unroll
        for (int j = 0; j < INRPE; j++) {
            qr0 = fmaf(a[j], wq0[j], qr0);
            qr1 = fmaf(a[j], wq1[j], qr1);
            kr0 = fmaf(a[j], wk0[j], kr0);
            kr1 = fmaf(a[j], wk1[j], kr1);
        }

        float2 qs = *(const float2*)&qkv[(size_t)s * QKVW + c0];        // pre-scaled q
        float2 kt = *(const float2*)&qkv[(size_t)t * QKVW + DH + c0];

        float c2 = (qs.x + qr0) * (kt.x + kr0) + (qs.y + qr1) * (kt.y + kr1);
        c2 += __shfl_xor(c2, 1, 64);
        c2 += __shfl_xor(c2, 2, 64);

        if ((lane & 3) == 0) compat[(size_t)e * HEADS + (lane >> 2)] = c2;
    }
}

// ---------------------------------------------------------------------------
// Kernel 2b: lightweight node-centric softmax + aggregate. One wave per node.
// Per edge: compat broadcast read (64B line), v float4 gather, online-softmax
// update. Unrolled x2 so consecutive edges' loads issue together.
// ---------------------------------------------------------------------------
__global__ __launch_bounds__(256) void node_attn2(
    const float* __restrict__ qkv, const float* __restrict__ compat,
    const int2* __restrict__ elist, const int* __restrict__ off,
    float* __restrict__ out, int Nn)
{
    int wave = threadIdx.x >> 6;
    int lane = threadIdx.x & 63;
    int n = blockIdx.x * 4 + wave;
    if (n >= Nn) return;

    int h = lane >> 2;
    int beg = off[n], end = off[n + 1];

    float m = -INFINITY, lsum = 0.0f;
    float4 o = make_float4(0.f, 0.f, 0.f, 0.f);

    int i = beg;
    for (; i + 1 < end; i += 2) {
        int2 e0 = elist[i];
        int2 e1 = elist[i + 1];
        float c0v = compat[(size_t)e0.x * HEADS + h];
        float c1v = compat[(size_t)e1.x * HEADS + h];
        float4 v0 = *(const float4*)&qkv[(size_t)e0.y * QKVW + 2 * DH + 4 * lane];
        float4 v1 = *(const float4*)&qkv[(size_t)e1.y * QKVW + 2 * DH + 4 * lane];

        float mn = fmaxf(m, c0v);
        float alpha = __expf(m - mn);
        float ex = __expf(c0v - mn);
        lsum = lsum * alpha + ex;
        o.x = fmaf(ex, v0.x, o.x * alpha);
        o.y = fmaf(ex, v0.y, o.y * alpha);
        o.z = fmaf(ex, v0.z, o.z * alpha);
        o.w = fmaf(ex, v0.w, o.w * alpha);
        m = mn;

        mn = fmaxf(m, c1v);
        alpha = __expf(m - mn);
        ex = __expf(c1v - mn);
        lsum = lsum * alpha + ex;
        o.x = fmaf(ex, v1.x, o.x * alpha);
        o.y = fmaf(ex, v1.y, o.y * alpha);
        o.z = fmaf(ex, v1.z, o.z * alpha);
        o.w = fmaf(ex, v1.w, o.w * alpha);
        m = mn;
    }
    if (i < end) {
        int2 e0 = elist[i];
        float c0v = compat[(size_t)e0.x * HEADS + h];
        float4 v0 = *(const float4*)&qkv[(size_t)e0.y * QKVW + 2 * DH + 4 * lane];
        float mn = fmaxf(m, c0v);
        float alpha = __expf(m - mn);
        float ex = __expf(c0v - mn);
        lsum = lsum * alpha + ex;
        o.x = fmaf(ex, v0.x, o.x * alpha);
        o.y = fmaf(ex, v0.y, o.y * alpha);
        o.z = fmaf(ex, v0.z, o.z * alpha);
        o.w = fmaf(ex, v0.w, o.w * alpha);
        m = mn;
    }

    float inv = 1.0f / (lsum + 1e-16f);   // deg=0 -> o=0 -> writes 0
    float4 r = make_float4(o.x * inv, o.y * inv, o.z * inv, o.w * inv);
    *(float4*)&out[(size_t)n * DIMX + 4 * lane] = r;
}

// ---------------------------------------------------------------------------
extern "C" void kernel_launch(void* const* d_in, const int* in_sizes, int n_in,
                              void* d_out, int out_size, void* d_ws, size_t ws_size,
                              hipStream_t stream)
{
    const float* x    = (const float*)d_in[0];
    const int*   ei   = (const int*)d_in[1];     // int32 (harness converts int64 -> int)
    const float* ea   = (const float*)d_in[2];
    const float* Wqkv = (const float*)d_in[3];
    const float* bqkv = (const float*)d_in[4];
    const float* Wk   = (const float*)d_in[5];
    const float* bk   = (const float*)d_in[6];
    const float* Wq   = (const float*)d_in[7];
    const float* bq   = (const float*)d_in[8];

    int Nn = in_sizes[0] / DIMX;
    int E  = in_sizes[1] / 2;
    float* out = (float*)d_out;

    // workspace layout
    float* qkv    = (float*)d_ws;                          // Nn*512 floats (102.4 MB)
    float* compat = qkv + (size_t)Nn * QKVW;               // E*16 floats (51.2 MB)
    int*   deg    = (int*)(compat + (size_t)E * HEADS);    // Nn
    int*   cur    = deg + Nn;                              // Nn
    int*   off    = cur + Nn;                              // Nn+1
    int2*  elist  = (int2*)(off + ((Nn + 2) & ~1));        // E int2 (6.4 MB)

    hipMemsetAsync(deg, 0, sizeof(int) * 2 * (size_t)Nn, stream);  // deg + cur

    qkv_gemm<<<dim3((Nn + 127) / 128, QKVW / 128), 256, 0, stream>>>(x, Wqkv, bqkv, qkv, Nn);
    count_kernel<<<(E + 255) / 256, 256, 0, stream>>>(ei, deg, E);
    scan_kernel<<<1, 1024, 0, stream>>>(deg, off, Nn);
    scatter_kernel<<<(E + 255) / 256, 256, 0, stream>>>(ei, off, cur, elist, E);
    compat_kernel<<<2048, 256, 0, stream>>>(qkv, ei, ea, Wq, bq, Wk, bk, compat, E);
    node_attn2<<<(Nn + 3) / 4, 256, 0, stream>>>(qkv, compat, elist, off, out, Nn);
}

// Round 4
// 880.258 us; speedup vs baseline: 1.0635x; 1.0635x over previous
//
#include <hip/hip_runtime.h>
#include <math.h>

// Problem constants (shapes follow the reference; N and E derived from in_sizes)
#define DIMX   256
#define HEADS  16
#define QKD    8
#define DH     128           // HEADS*QKD
#define QKVW   512           // 2*DH + DIMX
#define INRPE  18
#define SCALE  0.35355339059327373f   // 8^-0.5

// ---------------------------------------------------------------------------
// Kernel 1: qkv = x @ Wqkv + b ; q-part pre-scaled by SCALE.
// Row layout (512 floats): [q*SCALE (128) | k (128) | v (256)]
// 128x128 tile, 256 threads, 8x8 microtile.
// ---------------------------------------------------------------------------
__global__ __launch_bounds__(256) void qkv_gemm(
    const float* __restrict__ x, const float* __restrict__ W,
    const float* __restrict__ bias, float* __restrict__ qkv, int Nn)
{
    __shared__ float As[16][132];   // A^T tile: As[k][row]
    __shared__ float Bs[16][132];   // B tile:  Bs[k][col]

    int tid  = threadIdx.x;
    int row0 = blockIdx.x * 128;
    int col0 = blockIdx.y * 128;
    int tx = tid & 15, ty = tid >> 4;

    float acc[8][8] = {};

    for (int k0 = 0; k0 < DIMX; k0 += 16) {
        #pragma unroll
        for (int r = 0; r < 2; r++) {
            int idx  = tid + r * 256;
            int arow = idx >> 2, acol = (idx & 3) * 4;
            float4 av = make_float4(0.f, 0.f, 0.f, 0.f);
            int grow = row0 + arow;
            if (grow < Nn) av = *(const float4*)&x[(size_t)grow * DIMX + k0 + acol];
            As[acol + 0][arow] = av.x;
            As[acol + 1][arow] = av.y;
            As[acol + 2][arow] = av.z;
            As[acol + 3][arow] = av.w;
        }
        #pragma unroll
        for (int r = 0; r < 2; r++) {
            int idx  = tid + r * 256;
            int brow = idx >> 5, bcol = (idx & 31) * 4;
            *(float4*)&Bs[brow][bcol] =
                *(const float4*)&W[(size_t)(k0 + brow) * QKVW + col0 + bcol];
        }
        __syncthreads();
        #pragma unroll
        for (int kk = 0; kk < 16; kk++) {
            float a0[8], b0[8];
            *(float4*)&a0[0] = *(const float4*)&As[kk][ty * 8];
            *(float4*)&a0[4] = *(const float4*)&As[kk][ty * 8 + 4];
            *(float4*)&b0[0] = *(const float4*)&Bs[kk][tx * 4];
            *(float4*)&b0[4] = *(const float4*)&Bs[kk][64 + tx * 4];
            #pragma unroll
            for (int i = 0; i < 8; i++)
                #pragma unroll
                for (int j = 0; j < 8; j++)
                    acc[i][j] = fmaf(a0[i], b0[j], acc[i][j]);
        }
        __syncthreads();
    }

    float sc = (blockIdx.y == 0) ? SCALE : 1.0f;   // col block 0 is entirely q
    float4 bv0 = *(const float4*)&bias[col0 + tx * 4];
    float4 bv1 = *(const float4*)&bias[col0 + 64 + tx * 4];
    #pragma unroll
    for (int i = 0; i < 8; i++) {
        int grow = row0 + ty * 8 + i;
        if (grow < Nn) {
            float4 o0, o1;
            o0.x = (acc[i][0] + bv0.x) * sc;
            o0.y = (acc[i][1] + bv0.y) * sc;
            o0.z = (acc[i][2] + bv0.z) * sc;
            o0.w = (acc[i][3] + bv0.w) * sc;
            o1.x = (acc[i][4] + bv1.x) * sc;
            o1.y = (acc[i][5] + bv1.y) * sc;
            o1.z = (acc[i][6] + bv1.z) * sc;
            o1.w = (acc[i][7] + bv1.w) * sc;
            *(float4*)&qkv[(size_t)grow * QKVW + col0 + tx * 4] = o0;
            *(float4*)&qkv[(size_t)grow * QKVW + col0 + 64 + tx * 4] = o1;
        }
    }
}

// ---------------------------------------------------------------------------
// CSR build: count -> scan -> scatter (grouped by source node s)
// ---------------------------------------------------------------------------
__global__ void count_kernel(const int* __restrict__ ei, int* __restrict__ deg, int E)
{
    int e = blockIdx.x * blockDim.x + threadIdx.x;
    if (e < E) atomicAdd(&deg[ei[e]], 1);
}

__global__ __launch_bounds__(1024) void scan_kernel(
    const int* __restrict__ deg, int* __restrict__ off, int n)
{
    __shared__ int part[1024];
    int tid = threadIdx.x;
    int chunk = (n + 1023) / 1024;
    int s = tid * chunk;
    int epos = min(s + chunk, n);
    int sum = 0;
    for (int i = s; i < epos; i++) sum += deg[i];
    part[tid] = sum;
    __syncthreads();
    for (int d = 1; d < 1024; d <<= 1) {
        int v = (tid >= d) ? part[tid - d] : 0;
        __syncthreads();
        part[tid] += v;
        __syncthreads();
    }
    int run = part[tid] - sum;   // exclusive base
    for (int i = s; i < epos; i++) { off[i] = run; run += deg[i]; }
    if (tid == 1023) off[n] = run;
}

__global__ void scatter_kernel(const int* __restrict__ ei,
                               const int* __restrict__ off, int* __restrict__ cur,
                               int2* __restrict__ elist, int E)
{
    int e = blockIdx.x * blockDim.x + threadIdx.x;
    if (e < E) {
        int s = ei[e];
        int t = ei[E + e];
        int pos = atomicAdd(&cur[s], 1);
        elist[off[s] + pos] = make_int2(e, t);
    }
}

// ---------------------------------------------------------------------------
// Kernel 2: fused node-centric attention. One wave per node.
// Lane l -> head h=l>>2, qk dims 2l,2l+1; v dims 4l..4l+3.
// __launch_bounds__(256,3): VGPR budget 168 so the 72 RPE weight floats are
// genuinely register-resident (default budget 64 forced per-edge reloads —
// R3's latency bottleneck). Edge loop manually unrolled x2 with all loads
// (ea/k/v for both edges) hoisted ahead of the FMA chains for 2x MLP.
// ---------------------------------------------------------------------------
__global__ __launch_bounds__(256, 3) void node_attn(
    const float* __restrict__ qkv, const int2* __restrict__ elist,
    const int* __restrict__ off, const float* __restrict__ edge_attr,
    const float* __restrict__ Wq_rpe, const float* __restrict__ bq_rpe,
    const float* __restrict__ Wk_rpe, const float* __restrict__ bk_rpe,
    float* __restrict__ out, int Nn)
{
    int wave = threadIdx.x >> 6;
    int lane = threadIdx.x & 63;
    int n = blockIdx.x * 4 + wave;
    if (n >= Nn) return;

    int c0 = lane * 2;

    // resident RPE weight columns for this lane's two qk dims (72 VGPRs)
    float wq0[INRPE], wq1[INRPE], wk0[INRPE], wk1[INRPE];
    #pragma unroll
    for (int j = 0; j < INRPE; j++) {
        wq0[j] = Wq_rpe[j * DH + c0];
        wq1[j] = Wq_rpe[j * DH + c0 + 1];
        wk0[j] = Wk_rpe[j * DH + c0];
        wk1[j] = Wk_rpe[j * DH + c0 + 1];
    }
    float bq0 = bq_rpe[c0], bq1 = bq_rpe[c0 + 1];
    float bk0 = bk_rpe[c0], bk1 = bk_rpe[c0 + 1];

    float qs0 = qkv[(size_t)n * QKVW + c0];        // pre-scaled q
    float qs1 = qkv[(size_t)n * QKVW + c0 + 1];

    int beg = off[n], end = off[n + 1];

    float m = -INFINITY, lsum = 0.0f;
    float4 o = make_float4(0.f, 0.f, 0.f, 0.f);

    int i = beg;
    for (; i + 1 < end; i += 2) {
        int2 ed0 = elist[i];
        int2 ed1 = elist[i + 1];

        // ---- hoisted loads for both edges (ea: 9 float2 each; k float2; v float4)
        const float2* ea0p = (const float2*)(edge_attr + (size_t)ed0.x * INRPE);
        const float2* ea1p = (const float2*)(edge_attr + (size_t)ed1.x * INRPE);
        float2 a0[9], a1[9];
        #pragma unroll
        for (int j = 0; j < 9; j++) a0[j] = ea0p[j];
        #pragma unroll
        for (int j = 0; j < 9; j++) a1[j] = ea1p[j];
        float2 kt0 = *(const float2*)&qkv[(size_t)ed0.y * QKVW + DH + c0];
        float2 kt1 = *(const float2*)&qkv[(size_t)ed1.y * QKVW + DH + c0];
        float4 vt0 = *(const float4*)&qkv[(size_t)ed0.y * QKVW + 2 * DH + 4 * lane];
        float4 vt1 = *(const float4*)&qkv[(size_t)ed1.y * QKVW + 2 * DH + 4 * lane];

        // ---- RPE projections, both edges (8 independent FMA chains of 18)
        float q00 = bq0, q01 = bq1, k00 = bk0, k01 = bk1;
        float q10 = bq0, q11 = bq1, k10 = bk0, k11 = bk1;
        #pragma unroll
        for (int j = 0; j < 9; j++) {
            q00 = fmaf(a0[j].x, wq0[2*j], q00);  q00 = fmaf(a0[j].y, wq0[2*j+1], q00);
            q01 = fmaf(a0[j].x, wq1[2*j], q01);  q01 = fmaf(a0[j].y, wq1[2*j+1], q01);
            k00 = fmaf(a0[j].x, wk0[2*j], k00);  k00 = fmaf(a0[j].y, wk0[2*j+1], k00);
            k01 = fmaf(a0[j].x, wk1[2*j], k01);  k01 = fmaf(a0[j].y, wk1[2*j+1], k01);
            q10 = fmaf(a1[j].x, wq0[2*j], q10);  q10 = fmaf(a1[j].y, wq0[2*j+1], q10);
            q11 = fmaf(a1[j].x, wq1[2*j], q11);  q11 = fmaf(a1[j].y, wq1[2*j+1], q11);
            k10 = fmaf(a1[j].x, wk0[2*j], k10);  k10 = fmaf(a1[j].y, wk0[2*j+1], k10);
            k11 = fmaf(a1[j].x, wk1[2*j], k11);  k11 = fmaf(a1[j].y, wk1[2*j+1], k11);
        }

        float c0v = (qs0 + q00) * (kt0.x + k00) + (qs1 + q01) * (kt0.y + k01);
        float c1v = (qs0 + q10) * (kt1.x + k10) + (qs1 + q11) * (kt1.y + k11);
        c0v += __shfl_xor(c0v, 1, 64);
        c0v += __shfl_xor(c0v, 2, 64);
        c1v += __shfl_xor(c1v, 1, 64);
        c1v += __shfl_xor(c1v, 2, 64);

        // ---- sequential online-softmax updates (cheap)
        float mn = fmaxf(m, c0v);
        float alpha = __expf(m - mn);
        float ex = __expf(c0v - mn);
        lsum = lsum * alpha + ex;
        o.x = fmaf(ex, vt0.x, o.x * alpha);
        o.y = fmaf(ex, vt0.y, o.y * alpha);
        o.z = fmaf(ex, vt0.z, o.z * alpha);
        o.w = fmaf(ex, vt0.w, o.w * alpha);
        m = mn;

        mn = fmaxf(m, c1v);
        alpha = __expf(m - mn);
        ex = __expf(c1v - mn);
        lsum = lsum * alpha + ex;
        o.x = fmaf(ex, vt1.x, o.x * alpha);
        o.y = fmaf(ex, vt1.y, o.y * alpha);
        o.z = fmaf(ex, vt1.z, o.z * alpha);
        o.w = fmaf(ex, vt1.w, o.w * alpha);
        m = mn;
    }

    if (i < end) {   // odd remainder
        int2 ed0 = elist[i];
        const float2* ea0p = (const float2*)(edge_attr + (size_t)ed0.x * INRPE);
        float2 a0[9];
        #pragma unroll
        for (int j = 0; j < 9; j++) a0[j] = ea0p[j];
        float2 kt0 = *(const float2*)&qkv[(size_t)ed0.y * QKVW + DH + c0];
        float4 vt0 = *(const float4*)&qkv[(size_t)ed0.y * QKVW + 2 * DH + 4 * lane];

        float q00 = bq0, q01 = bq1, k00 = bk0, k01 = bk1;
        #pragma unroll
        for (int j = 0; j < 9; j++) {
            q00 = fmaf(a0[j].x, wq0[2*j], q00);  q00 = fmaf(a0[j].y, wq0[2*j+1], q00);
            q01 = fmaf(a0[j].x, wq1[2*j], q01);  q01 = fmaf(a0[j].y, wq1[2*j+1], q01);
            k00 = fmaf(a0[j].x, wk0[2*j], k00);  k00 = fmaf(a0[j].y, wk0[2*j+1], k00);
            k01 = fmaf(a0[j].x, wk1[2*j], k01);  k01 = fmaf(a0[j].y, wk1[2*j+1], k01);
        }
        float c0v = (qs0 + q00) * (kt0.x + k00) + (qs1 + q01) * (kt0.y + k01);
        c0v += __shfl_xor(c0v, 1, 64);
        c0v += __shfl_xor(c0v, 2, 64);

        float mn = fmaxf(m, c0v);
        float alpha = __expf(m - mn);
        float ex = __expf(c0v - mn);
        lsum = lsum * alpha + ex;
        o.x = fmaf(ex, vt0.x, o.x * alpha);
        o.y = fmaf(ex, vt0.y, o.y * alpha);
        o.z = fmaf(ex, vt0.z, o.z * alpha);
        o.w = fmaf(ex, vt0.w, o.w * alpha);
        m = mn;
    }

    float inv = 1.0f / (lsum + 1e-16f);   // deg=0 -> o=0 -> writes 0
    float4 r = make_float4(o.x * inv, o.y * inv, o.z * inv, o.w * inv);
    *(float4*)&out[(size_t)n * DIMX + 4 * lane] = r;
}

// ---------------------------------------------------------------------------
extern "C" void kernel_launch(void* const* d_in, const int* in_sizes, int n_in,
                              void* d_out, int out_size, void* d_ws, size_t ws_size,
                              hipStream_t stream)
{
    const float* x    = (const float*)d_in[0];
    const int*   ei   = (const int*)d_in[1];     // int32 (harness converts int64 -> int)
    const float* ea   = (const float*)d_in[2];
    const float* Wqkv = (const float*)d_in[3];
    const float* bqkv = (const float*)d_in[4];
    const float* Wk   = (const float*)d_in[5];
    const float* bk   = (const float*)d_in[6];
    const float* Wq   = (const float*)d_in[7];
    const float* bq   = (const float*)d_in[8];

    int Nn = in_sizes[0] / DIMX;
    int E  = in_sizes[1] / 2;
    float* out = (float*)d_out;

    // workspace layout
    float* qkv   = (float*)d_ws;                          // Nn*512 floats (102.4 MB)
    int*   deg   = (int*)d_ws + (size_t)Nn * QKVW;        // Nn
    int*   cur   = deg + Nn;                              // Nn
    int*   off   = cur + Nn;                              // Nn+1
    int2*  elist = (int2*)(off + ((Nn + 2) & ~1));        // E int2 (6.4 MB)

    hipMemsetAsync(deg, 0, sizeof(int) * 2 * (size_t)Nn, stream);  // deg + cur

    qkv_gemm<<<dim3((Nn + 127) / 128, QKVW / 128), 256, 0, stream>>>(x, Wqkv, bqkv, qkv, Nn);
    count_kernel<<<(E + 255) / 256, 256, 0, stream>>>(ei, deg, E);
    scan_kernel<<<1, 1024, 0, stream>>>(deg, off, Nn);
    scatter_kernel<<<(E + 255) / 256, 256, 0, stream>>>(ei, off, cur, elist, E);
    node_attn<<<(Nn + 3) / 4, 256, 0, stream>>>(qkv, elist, off, ea, Wq, bq, Wk, bk, out, Nn);
}

// Round 5
// 878.605 us; speedup vs baseline: 1.0655x; 1.0019x over previous
//
#include <hip/hip_runtime.h>
#include <math.h>

// Problem constants (shapes follow the reference; N and E derived from in_sizes)
#define DIMX   256
#define HEADS  16
#define QKD    8
#define DH     128           // HEADS*QKD
#define QKVW   512           // 2*DH + DIMX
#define INRPE  18
#define SCALE  0.35355339059327373f   // 8^-0.5

// Force a value to live in a VGPR: opaque to the optimizer, cannot be
// rematerialized as a reload. (R3/R4 evidence: without this the compiler
// keeps VGPR_Count at 64 and re-loads all 72 RPE weights every edge.)
#define PIN(x) asm volatile("" : "+v"(x))

// ---------------------------------------------------------------------------
// Kernel 1: qkv = x @ Wqkv + b ; q-part pre-scaled by SCALE.
// Row layout (512 floats): [q*SCALE (128) | k (128) | v (256)]
// 128x128 tile, 256 threads, 8x8 microtile.
// ---------------------------------------------------------------------------
__global__ __launch_bounds__(256) void qkv_gemm(
    const float* __restrict__ x, const float* __restrict__ W,
    const float* __restrict__ bias, float* __restrict__ qkv, int Nn)
{
    __shared__ float As[16][132];   // A^T tile: As[k][row]
    __shared__ float Bs[16][132];   // B tile:  Bs[k][col]

    int tid  = threadIdx.x;
    int row0 = blockIdx.x * 128;
    int col0 = blockIdx.y * 128;
    int tx = tid & 15, ty = tid >> 4;

    float acc[8][8] = {};

    for (int k0 = 0; k0 < DIMX; k0 += 16) {
        #pragma unroll
        for (int r = 0; r < 2; r++) {
            int idx  = tid + r * 256;
            int arow = idx >> 2, acol = (idx & 3) * 4;
            float4 av = make_float4(0.f, 0.f, 0.f, 0.f);
            int grow = row0 + arow;
            if (grow < Nn) av = *(const float4*)&x[(size_t)grow * DIMX + k0 + acol];
            As[acol + 0][arow] = av.x;
            As[acol + 1][arow] = av.y;
            As[acol + 2][arow] = av.z;
            As[acol + 3][arow] = av.w;
        }
        #pragma unroll
        for (int r = 0; r < 2; r++) {
            int idx  = tid + r * 256;
            int brow = idx >> 5, bcol = (idx & 31) * 4;
            *(float4*)&Bs[brow][bcol] =
                *(const float4*)&W[(size_t)(k0 + brow) * QKVW + col0 + bcol];
        }
        __syncthreads();
        #pragma unroll
        for (int kk = 0; kk < 16; kk++) {
            float a0[8], b0[8];
            *(float4*)&a0[0] = *(const float4*)&As[kk][ty * 8];
            *(float4*)&a0[4] = *(const float4*)&As[kk][ty * 8 + 4];
            *(float4*)&b0[0] = *(const float4*)&Bs[kk][tx * 4];
            *(float4*)&b0[4] = *(const float4*)&Bs[kk][64 + tx * 4];
            #pragma unroll
            for (int i = 0; i < 8; i++)
                #pragma unroll
                for (int j = 0; j < 8; j++)
                    acc[i][j] = fmaf(a0[i], b0[j], acc[i][j]);
        }
        __syncthreads();
    }

    float sc = (blockIdx.y == 0) ? SCALE : 1.0f;   // col block 0 is entirely q
    float4 bv0 = *(const float4*)&bias[col0 + tx * 4];
    float4 bv1 = *(const float4*)&bias[col0 + 64 + tx * 4];
    #pragma unroll
    for (int i = 0; i < 8; i++) {
        int grow = row0 + ty * 8 + i;
        if (grow < Nn) {
            float4 o0, o1;
            o0.x = (acc[i][0] + bv0.x) * sc;
            o0.y = (acc[i][1] + bv0.y) * sc;
            o0.z = (acc[i][2] + bv0.z) * sc;
            o0.w = (acc[i][3] + bv0.w) * sc;
            o1.x = (acc[i][4] + bv1.x) * sc;
            o1.y = (acc[i][5] + bv1.y) * sc;
            o1.z = (acc[i][6] + bv1.z) * sc;
            o1.w = (acc[i][7] + bv1.w) * sc;
            *(float4*)&qkv[(size_t)grow * QKVW + col0 + tx * 4] = o0;
            *(float4*)&qkv[(size_t)grow * QKVW + col0 + 64 + tx * 4] = o1;
        }
    }
}

// ---------------------------------------------------------------------------
// CSR build: count -> scan -> scatter (grouped by source node s)
// ---------------------------------------------------------------------------
__global__ void count_kernel(const int* __restrict__ ei, int* __restrict__ deg, int E)
{
    int e = blockIdx.x * blockDim.x + threadIdx.x;
    if (e < E) atomicAdd(&deg[ei[e]], 1);
}

__global__ __launch_bounds__(1024) void scan_kernel(
    const int* __restrict__ deg, int* __restrict__ off, int n)
{
    __shared__ int part[1024];
    int tid = threadIdx.x;
    int chunk = (n + 1023) / 1024;
    int s = tid * chunk;
    int epos = min(s + chunk, n);
    int sum = 0;
    for (int i = s; i < epos; i++) sum += deg[i];
    part[tid] = sum;
    __syncthreads();
    for (int d = 1; d < 1024; d <<= 1) {
        int v = (tid >= d) ? part[tid - d] : 0;
        __syncthreads();
        part[tid] += v;
        __syncthreads();
    }
    int run = part[tid] - sum;   // exclusive base
    for (int i = s; i < epos; i++) { off[i] = run; run += deg[i]; }
    if (tid == 1023) off[n] = run;
}

__global__ void scatter_kernel(const int* __restrict__ ei,
                               const int* __restrict__ off, int* __restrict__ cur,
                               int2* __restrict__ elist, int E)
{
    int e = blockIdx.x * blockDim.x + threadIdx.x;
    if (e < E) {
        int s = ei[e];
        int t = ei[E + e];
        int pos = atomicAdd(&cur[s], 1);
        elist[off[s] + pos] = make_int2(e, t);
    }
}

// ---------------------------------------------------------------------------
// Kernel 2: fused node-centric attention. One wave per node.
// Lane l -> head h=l>>2, qk dims 2l,2l+1; v dims 4l..4l+3.
// RPE weights loaded once and PINNED into VGPRs (76 floats). Edge loop
// unrolled x2 with both edges' loads hoisted for memory-level parallelism.
// ---------------------------------------------------------------------------
__global__ __launch_bounds__(256, 3) void node_attn(
    const float* __restrict__ qkv, const int2* __restrict__ elist,
    const int* __restrict__ off, const float* __restrict__ edge_attr,
    const float* __restrict__ Wq_rpe, const float* __restrict__ bq_rpe,
    const float* __restrict__ Wk_rpe, const float* __restrict__ bk_rpe,
    float* __restrict__ out, int Nn)
{
    int wave = threadIdx.x >> 6;
    int lane = threadIdx.x & 63;
    int n = blockIdx.x * 4 + wave;
    if (n >= Nn) return;

    int c0 = lane * 2;

    // resident RPE weight columns for this lane's two qk dims (72 VGPRs, pinned)
    float wq0[INRPE], wq1[INRPE], wk0[INRPE], wk1[INRPE];
    #pragma unroll
    for (int j = 0; j < INRPE; j++) {
        wq0[j] = Wq_rpe[j * DH + c0];
        wq1[j] = Wq_rpe[j * DH + c0 + 1];
        wk0[j] = Wk_rpe[j * DH + c0];
        wk1[j] = Wk_rpe[j * DH + c0 + 1];
        PIN(wq0[j]); PIN(wq1[j]); PIN(wk0[j]); PIN(wk1[j]);
    }
    float bq0 = bq_rpe[c0], bq1 = bq_rpe[c0 + 1];
    float bk0 = bk_rpe[c0], bk1 = bk_rpe[c0 + 1];
    PIN(bq0); PIN(bq1); PIN(bk0); PIN(bk1);

    float qs0 = qkv[(size_t)n * QKVW + c0];        // pre-scaled q
    float qs1 = qkv[(size_t)n * QKVW + c0 + 1];
    PIN(qs0); PIN(qs1);

    int beg = off[n], end = off[n + 1];

    float m = -INFINITY, lsum = 0.0f;
    float4 o = make_float4(0.f, 0.f, 0.f, 0.f);

    int i = beg;
    for (; i + 1 < end; i += 2) {
        int2 ed0 = elist[i];
        int2 ed1 = elist[i + 1];

        // ---- hoisted loads for both edges (ea: 9 float2 each; k float2; v float4)
        const float2* ea0p = (const float2*)(edge_attr + (size_t)ed0.x * INRPE);
        const float2* ea1p = (const float2*)(edge_attr + (size_t)ed1.x * INRPE);
        float2 a0[9], a1[9];
        #pragma unroll
        for (int j = 0; j < 9; j++) a0[j] = ea0p[j];
        #pragma unroll
        for (int j = 0; j < 9; j++) a1[j] = ea1p[j];
        float2 kt0 = *(const float2*)&qkv[(size_t)ed0.y * QKVW + DH + c0];
        float2 kt1 = *(const float2*)&qkv[(size_t)ed1.y * QKVW + DH + c0];
        float4 vt0 = *(const float4*)&qkv[(size_t)ed0.y * QKVW + 2 * DH + 4 * lane];
        float4 vt1 = *(const float4*)&qkv[(size_t)ed1.y * QKVW + 2 * DH + 4 * lane];

        // ---- RPE projections, both edges (8 independent FMA chains of 18)
        float q00 = bq0, q01 = bq1, k00 = bk0, k01 = bk1;
        float q10 = bq0, q11 = bq1, k10 = bk0, k11 = bk1;
        #pragma unroll
        for (int j = 0; j < 9; j++) {
            q00 = fmaf(a0[j].x, wq0[2*j], q00);  q00 = fmaf(a0[j].y, wq0[2*j+1], q00);
            q01 = fmaf(a0[j].x, wq1[2*j], q01);  q01 = fmaf(a0[j].y, wq1[2*j+1], q01);
            k00 = fmaf(a0[j].x, wk0[2*j], k00);  k00 = fmaf(a0[j].y, wk0[2*j+1], k00);
            k01 = fmaf(a0[j].x, wk1[2*j], k01);  k01 = fmaf(a0[j].y, wk1[2*j+1], k01);
            q10 = fmaf(a1[j].x, wq0[2*j], q10);  q10 = fmaf(a1[j].y, wq0[2*j+1], q10);
            q11 = fmaf(a1[j].x, wq1[2*j], q11);  q11 = fmaf(a1[j].y, wq1[2*j+1], q11);
            k10 = fmaf(a1[j].x, wk0[2*j], k10);  k10 = fmaf(a1[j].y, wk0[2*j+1], k10);
            k11 = fmaf(a1[j].x, wk1[2*j], k11);  k11 = fmaf(a1[j].y, wk1[2*j+1], k11);
        }

        float c0v = (qs0 + q00) * (kt0.x + k00) + (qs1 + q01) * (kt0.y + k01);
        float c1v = (qs0 + q10) * (kt1.x + k10) + (qs1 + q11) * (kt1.y + k11);
        c0v += __shfl_xor(c0v, 1, 64);
        c0v += __shfl_xor(c0v, 2, 64);
        c1v += __shfl_xor(c1v, 1, 64);
        c1v += __shfl_xor(c1v, 2, 64);

        // ---- sequential online-softmax updates (cheap)
        float mn = fmaxf(m, c0v);
        float alpha = __expf(m - mn);
        float ex = __expf(c0v - mn);
        lsum = lsum * alpha + ex;
        o.x = fmaf(ex, vt0.x, o.x * alpha);
        o.y = fmaf(ex, vt0.y, o.y * alpha);
        o.z = fmaf(ex, vt0.z, o.z * alpha);
        o.w = fmaf(ex, vt0.w, o.w * alpha);
        m = mn;

        mn = fmaxf(m, c1v);
        alpha = __expf(m - mn);
        ex = __expf(c1v - mn);
        lsum = lsum * alpha + ex;
        o.x = fmaf(ex, vt1.x, o.x * alpha);
        o.y = fmaf(ex, vt1.y, o.y * alpha);
        o.z = fmaf(ex, vt1.z, o.z * alpha);
        o.w = fmaf(ex, vt1.w, o.w * alpha);
        m = mn;
    }

    if (i < end) {   // odd remainder
        int2 ed0 = elist[i];
        const float2* ea0p = (const float2*)(edge_attr + (size_t)ed0.x * INRPE);
        float2 a0[9];
        #pragma unroll
        for (int j = 0; j < 9; j++) a0[j] = ea0p[j];
        float2 kt0 = *(const float2*)&qkv[(size_t)ed0.y * QKVW + DH + c0];
        float4 vt0 = *(const float4*)&qkv[(size_t)ed0.y * QKVW + 2 * DH + 4 * lane];

        float q00 = bq0, q01 = bq1, k00 = bk0, k01 = bk1;
        #pragma unroll
        for (int j = 0; j < 9; j++) {
            q00 = fmaf(a0[j].x, wq0[2*j], q00);  q00 = fmaf(a0[j].y, wq0[2*j+1], q00);
            q01 = fmaf(a0[j].x, wq1[2*j], q01);  q01 = fmaf(a0[j].y, wq1[2*j+1], q01);
            k00 = fmaf(a0[j].x, wk0[2*j], k00);  k00 = fmaf(a0[j].y, wk0[2*j+1], k00);
            k01 = fmaf(a0[j].x, wk1[2*j], k01);  k01 = fmaf(a0[j].y, wk1[2*j+1], k01);
        }
        float c0v = (qs0 + q00) * (kt0.x + k00) + (qs1 + q01) * (kt0.y + k01);
        c0v += __shfl_xor(c0v, 1, 64);
        c0v += __shfl_xor(c0v, 2, 64);

        float mn = fmaxf(m, c0v);
        float alpha = __expf(m - mn);
        float ex = __expf(c0v - mn);
        lsum = lsum * alpha + ex;
        o.x = fmaf(ex, vt0.x, o.x * alpha);
        o.y = fmaf(ex, vt0.y, o.y * alpha);
        o.z = fmaf(ex, vt0.z, o.z * alpha);
        o.w = fmaf(ex, vt0.w, o.w * alpha);
        m = mn;
    }

    float inv = 1.0f / (lsum + 1e-16f);   // deg=0 -> o=0 -> writes 0
    float4 r = make_float4(o.x * inv, o.y * inv, o.z * inv, o.w * inv);
    *(float4*)&out[(size_t)n * DIMX + 4 * lane] = r;
}

// ---------------------------------------------------------------------------
extern "C" void kernel_launch(void* const* d_in, const int* in_sizes, int n_in,
                              void* d_out, int out_size, void* d_ws, size_t ws_size,
                              hipStream_t stream)
{
    const float* x    = (const float*)d_in[0];
    const int*   ei   = (const int*)d_in[1];     // int32 (harness converts int64 -> int)
    const float* ea   = (const float*)d_in[2];
    const float* Wqkv = (const float*)d_in[3];
    const float* bqkv = (const float*)d_in[4];
    const float* Wk   = (const float*)d_in[5];
    const float* bk   = (const float*)d_in[6];
    const float* Wq   = (const float*)d_in[7];
    const float* bq   = (const float*)d_in[8];

    int Nn = in_sizes[0] / DIMX;
    int E  = in_sizes[1] / 2;
    float* out = (float*)d_out;

    // workspace layout
    float* qkv   = (float*)d_ws;                          // Nn*512 floats (102.4 MB)
    int*   deg   = (int*)d_ws + (size_t)Nn * QKVW;        // Nn
    int*   cur   = deg + Nn;                              // Nn
    int*   off   = cur + Nn;                              // Nn+1
    int2*  elist = (int2*)(off + ((Nn + 2) & ~1));        // E int2 (6.4 MB)

    hipMemsetAsync(deg, 0, sizeof(int) * 2 * (size_t)Nn, stream);  // deg + cur

    qkv_gemm<<<dim3((Nn + 127) / 128, QKVW / 128), 256, 0, stream>>>(x, Wqkv, bqkv, qkv, Nn);
    count_kernel<<<(E + 255) / 256, 256, 0, stream>>>(ei, deg, E);
    scan_kernel<<<1, 1024, 0, stream>>>(deg, off, Nn);
    scatter_kernel<<<(E + 255) / 256, 256, 0, stream>>>(ei, off, cur, elist, E);
    node_attn<<<(Nn + 3) / 4, 256, 0, stream>>>(qkv, elist, off, ea, Wq, bq, Wk, bk, out, Nn);
}